// Round 3
// baseline (311.862 us; speedup 1.0000x reference)
//
#include <hip/hip_runtime.h>
#include <hip/hip_bf16.h>

// Problem sizes (fixed by reference setup_inputs):
//   B=16, N_LOG=512, N_PHYS(Q)=2048, E=2048
#define BATCH 16
#define NLOG 512
#define Q 2048
#define NEDGE 2048
#define M_TOT (BATCH * NLOG)   // 8192 GEMM rows
#define K_TOT Q                // 2048
#define N_TOT Q                // 2048

typedef short short8 __attribute__((ext_vector_type(8)));
typedef float f32x4 __attribute__((ext_vector_type(4)));
typedef unsigned short us8 __attribute__((ext_vector_type(8)));

// ---------------------------------------------------------------------------
// K1: convert P (fp32) -> Pb (bf16). 16.78M elements, 4 per thread.
__global__ __launch_bounds__(256) void cvt_p(const float* __restrict__ P,
                                             __hip_bfloat16* __restrict__ Pb) {
    int i = (blockIdx.x * 256 + threadIdx.x) * 4;
    float4 v = *(const float4*)(P + i);
    Pb[i + 0] = __float2bfloat16(v.x);
    Pb[i + 1] = __float2bfloat16(v.y);
    Pb[i + 2] = __float2bfloat16(v.z);
    Pb[i + 3] = __float2bfloat16(v.w);
}

// ---------------------------------------------------------------------------
// K2: build Abt[q][p] = (d_hw[p][q] == 1) ? 1 : 0 (bf16), via 32x32 LDS
// transpose so both global read and write are coalesced.
__global__ __launch_bounds__(256) void build_abt(const int* __restrict__ d_hw,
                                                 __hip_bfloat16* __restrict__ Abt) {
    __shared__ __hip_bfloat16 tile[32][33];
    int q0 = blockIdx.x * 32;
    int p0 = blockIdx.y * 32;
    int tx = threadIdx.x & 31;
    int ty = threadIdx.x >> 5;  // 0..7
    for (int s = 0; s < 32; s += 8) {
        int p = p0 + ty + s;
        int v = d_hw[(size_t)p * Q + q0 + tx];
        tile[ty + s][tx] = __float2bfloat16(v == 1 ? 1.0f : 0.0f);
    }
    __syncthreads();
    for (int s = 0; s < 32; s += 8) {
        Abt[(size_t)(q0 + ty + s) * Q + p0 + tx] = tile[tx][ty + s];
    }
}

// ---------------------------------------------------------------------------
// K3: GEMM  C[M,N] = A[M,K] * Bt[N,K]^T  (bf16 in, fp32 acc, bf16 out).
// 128x128 C-tile / 256-thread block, 2x2 waves, each wave 4x4 of 16x16x32.
// A staged through LDS (XOR-swizzled, conflict-free); B fragments loaded
// DIRECTLY from global (L2-resident) with a register double-buffer, halving
// LDS read traffic (the measured structural bottleneck: 256 cyc LDS vs 78
// cyc MFMA per block-iter at r=0.5 reads/MFMA).
__global__ __launch_bounds__(256) void gemm_bt(const short* __restrict__ A,
                                               const short* __restrict__ Bt,
                                               __hip_bfloat16* __restrict__ C) {
    __shared__ short As[4096];           // 128 rows x 32 k (chunk-swizzled)

    const int t = threadIdx.x;
    const int w = t >> 6;                // wave 0..3
    const int wr = w >> 1, wc = w & 1;   // 2x2 wave grid
    const int l = t & 63;
    const int quad = l >> 4;             // 0..3
    const int lane16 = l & 15;

    const int m0 = blockIdx.x * 128;
    const int n0 = blockIdx.y * 128;

    // A staging: thread t covers row s_row (64B), 16B chunk (t&3), with the
    // global source chunk XOR-swizzled so LDS physical chunk cp at row r
    // holds logical chunk cp ^ ((r>>1)&3). 2 calls/iter cover 128 rows.
    const int s_row = t >> 2;                          // 0..63
    const int s_col = ((t & 3) ^ ((t >> 3) & 3)) * 8;  // swizzled k-offset

    // A fragment read: logical chunk `quad` lives at physical chunk
    // quad ^ ((row>>1)&3) = quad ^ ((lane16>>1)&3)  (row = wr*64+i*16+lane16).
    const int a_chunk = (quad ^ ((lane16 >> 1) & 3)) * 8;

    // B fragment base pointers (direct global; 16 distinct 64B lines/load,
    // same line count as a coalesced load).
    const short* bp[4];
    #pragma unroll
    for (int j = 0; j < 4; j++)
        bp[j] = Bt + (size_t)(n0 + wc * 64 + j * 16 + lane16) * K_TOT + quad * 8;

    f32x4 acc[4][4] = {};
    short8 bcur[4], bnxt[4];
    #pragma unroll
    for (int j = 0; j < 4; j++) bcur[j] = *(const short8*)(bp[j]);

    for (int k0 = 0; k0 < K_TOT; k0 += 32) {
        const short* gA0 = A + (size_t)(m0 + s_row) * K_TOT + k0 + s_col;
        const short* gA1 = A + (size_t)(m0 + 64 + s_row) * K_TOT + k0 + s_col;
        __builtin_amdgcn_global_load_lds(
            (const __attribute__((address_space(1))) void*)gA0,
            (__attribute__((address_space(3))) void*)(As + w * 512), 16, 0, 0);
        __builtin_amdgcn_global_load_lds(
            (const __attribute__((address_space(1))) void*)gA1,
            (__attribute__((address_space(3))) void*)(As + 2048 + w * 512), 16, 0, 0);
        __syncthreads();

        // prefetch next-iter B into registers; overlaps the MFMA phase
        if (k0 + 32 < K_TOT) {
            #pragma unroll
            for (int j = 0; j < 4; j++)
                bnxt[j] = *(const short8*)(bp[j] + k0 + 32);
        }

        short8 af[4];
        #pragma unroll
        for (int i = 0; i < 4; i++)
            af[i] = *(const short8*)(As + (wr * 64 + i * 16 + lane16) * 32 + a_chunk);

        #pragma unroll
        for (int i = 0; i < 4; i++)
            #pragma unroll
            for (int j = 0; j < 4; j++)
                acc[i][j] = __builtin_amdgcn_mfma_f32_16x16x32_bf16(
                    af[i], bcur[j], acc[i][j], 0, 0, 0);
        __syncthreads();

        #pragma unroll
        for (int j = 0; j < 4; j++) bcur[j] = bnxt[j];
    }

    // epilogue: C/D layout col = lane&15, row = quad*4 + reg
    #pragma unroll
    for (int i = 0; i < 4; i++) {
        #pragma unroll
        for (int j = 0; j < 4; j++) {
            #pragma unroll
            for (int r = 0; r < 4; r++) {
                int row = m0 + wr * 64 + i * 16 + quad * 4 + r;
                int col = n0 + wc * 64 + j * 16 + lane16;
                C[(size_t)row * N_TOT + col] = __float2bfloat16(acc[i][j][r]);
            }
        }
    }
}

// ---------------------------------------------------------------------------
// K4: per-edge dot. One wave per 4 edges; block = 4 waves = 16 edges of one
// batch. Lane l reads 4x16B chunks per row (whole Q=2048 row per wave,
// coalesced). One shuffle-reduce covers all 4 weighted dots (linearity).
// Also accumulates sum_e w (wave-uniform, free) for the finalize divide.
#define EPB 16   // edges per block
__global__ __launch_bounds__(256) void edge_dot(const __hip_bfloat16* __restrict__ PAb,
                                                const __hip_bfloat16* __restrict__ Pb,
                                                const int* __restrict__ esrc,
                                                const int* __restrict__ edst,
                                                const float* __restrict__ ew,
                                                float* __restrict__ adj_acc,
                                                float* __restrict__ wsum_acc) {
    const int b = blockIdx.y;
    const int t = threadIdx.x;
    const int w = t >> 6;
    const int l = t & 63;
    const int e_base = blockIdx.x * EPB + w * 4;

    const unsigned short* PAbase = (const unsigned short*)PAb + (size_t)b * NLOG * Q;
    const unsigned short* Pbase  = (const unsigned short*)Pb  + (size_t)b * NLOG * Q;

    float accw = 0.f, wsumw = 0.f;
    #pragma unroll
    for (int k = 0; k < 4; k++) {
        int e = e_base + k;
        int src = esrc[b * NEDGE + e];
        int dst = edst[b * NEDGE + e];
        float wgt = ew[b * NEDGE + e];
        wsumw += wgt;
        const unsigned short* gi = PAbase + (size_t)src * Q + l * 8;
        const unsigned short* gj = Pbase  + (size_t)dst * Q + l * 8;
        float s = 0.f;
        #pragma unroll
        for (int c = 0; c < 4; c++) {
            us8 a = *(const us8*)(gi + c * 512);
            us8 bb = *(const us8*)(gj + c * 512);
            #pragma unroll
            for (int u = 0; u < 8; u++) {
                float fa = __uint_as_float((unsigned)a[u] << 16);
                float fb = __uint_as_float((unsigned)bb[u] << 16);
                s += fa * fb;
            }
        }
        accw += wgt * s;
    }
    #pragma unroll
    for (int off = 32; off > 0; off >>= 1) accw += __shfl_xor(accw, off);
    __shared__ float wred[4], wred2[4];
    if (l == 0) { wred[w] = accw; wred2[w] = wsumw; }
    __syncthreads();
    if (t == 0) {
        atomicAdd(&adj_acc[b], wred[0] + wred[1] + wred[2] + wred[3]);
        atomicAdd(&wsum_acc[b], wred2[0] + wred2[1] + wred2[2] + wred2[3]);
    }
}

// ---------------------------------------------------------------------------
// K5: loss = -mean_b( adj[b] / max(wsum[b], eps) )  — trivial now.
__global__ __launch_bounds__(64) void finalize(const float* __restrict__ adj_acc,
                                               const float* __restrict__ wsum_acc,
                                               float* __restrict__ out) {
    if (threadIdx.x == 0) {
        float s = 0.f;
        #pragma unroll
        for (int b = 0; b < BATCH; b++)
            s += adj_acc[b] / fmaxf(wsum_acc[b], 1e-8f);
        out[0] = -s / (float)BATCH;
    }
}

// ---------------------------------------------------------------------------
extern "C" void kernel_launch(void* const* d_in, const int* in_sizes, int n_in,
                              void* d_out, int out_size, void* d_ws, size_t ws_size,
                              hipStream_t stream) {
    const float* P    = (const float*)d_in[0];
    const int* d_hw   = (const int*)d_in[1];
    const int* esrc   = (const int*)d_in[2];
    const int* edst   = (const int*)d_in[3];
    const float* ew   = (const float*)d_in[4];
    float* out        = (float*)d_out;

    char* ws = (char*)d_ws;
    // workspace layout (bytes):
    //   Pb   : bf16 [B*N*Q]  = 33,554,432
    //   Abt  : bf16 [Q*Q]    =  8,388,608  (offset 33,554,432)
    //   PAb  : bf16 [B*N*Q]  = 33,554,432  (offset 41,943,040)
    //   adj  : f32 [16]                     (offset 75,497,472)
    //   wsum : f32 [16]                     (offset 75,497,536)
    __hip_bfloat16* Pb  = (__hip_bfloat16*)ws;
    __hip_bfloat16* Abt = (__hip_bfloat16*)(ws + 33554432);
    __hip_bfloat16* PAb = (__hip_bfloat16*)(ws + 41943040);
    float* adj          = (float*)(ws + 75497472);
    float* wsum         = (float*)(ws + 75497536);

    hipMemsetAsync(adj, 0, 2 * BATCH * sizeof(float), stream);

    cvt_p<<<M_TOT * Q / (256 * 4), 256, 0, stream>>>(P, Pb);
    build_abt<<<dim3(Q / 32, Q / 32), 256, 0, stream>>>(d_hw, Abt);
    gemm_bt<<<dim3(M_TOT / 128, N_TOT / 128), 256, 0, stream>>>(
        (const short*)Pb, (const short*)Abt, PAb);
    edge_dot<<<dim3(NEDGE / EPB, BATCH), 256, 0, stream>>>(
        PAb, Pb, esrc, edst, ew, adj, wsum);
    finalize<<<1, 64, 0, stream>>>(adj, wsum, out);
}

// Round 4
// 235.298 us; speedup vs baseline: 1.3254x; 1.3254x over previous
//
#include <hip/hip_runtime.h>
#include <hip/hip_bf16.h>

// Problem sizes (fixed by reference setup_inputs):
//   B=16, N_LOG=512, N_PHYS(Q)=2048, E=2048
#define BATCH 16
#define NLOG 512
#define Q 2048
#define NEDGE 2048
#define M_TOT (BATCH * NLOG)   // 8192 GEMM rows
#define K_TOT Q                // 2048
#define N_TOT Q                // 2048

typedef short short8 __attribute__((ext_vector_type(8)));
typedef float f32x4 __attribute__((ext_vector_type(4)));
typedef unsigned short us8 __attribute__((ext_vector_type(8)));

// ---------------------------------------------------------------------------
// K1: convert P (fp32) -> Pb (bf16). 16.78M elements, 8 per thread.
__global__ __launch_bounds__(256) void cvt_p(const float* __restrict__ P,
                                             __hip_bfloat16* __restrict__ Pb) {
    int i = (blockIdx.x * 256 + threadIdx.x) * 8;
    float4 v0 = *(const float4*)(P + i);
    float4 v1 = *(const float4*)(P + i + 4);
    Pb[i + 0] = __float2bfloat16(v0.x);
    Pb[i + 1] = __float2bfloat16(v0.y);
    Pb[i + 2] = __float2bfloat16(v0.z);
    Pb[i + 3] = __float2bfloat16(v0.w);
    Pb[i + 4] = __float2bfloat16(v1.x);
    Pb[i + 5] = __float2bfloat16(v1.y);
    Pb[i + 6] = __float2bfloat16(v1.z);
    Pb[i + 7] = __float2bfloat16(v1.w);
}

// ---------------------------------------------------------------------------
// K2: build Abt[q][p] = (d_hw[p][q] == 1) ? 1 : 0 (bf16), via 32x32 LDS
// transpose so both global read and write are coalesced.
__global__ __launch_bounds__(256) void build_abt(const int* __restrict__ d_hw,
                                                 __hip_bfloat16* __restrict__ Abt) {
    __shared__ __hip_bfloat16 tile[32][33];
    int q0 = blockIdx.x * 32;
    int p0 = blockIdx.y * 32;
    int tx = threadIdx.x & 31;
    int ty = threadIdx.x >> 5;  // 0..7
    for (int s = 0; s < 32; s += 8) {
        int p = p0 + ty + s;
        int v = d_hw[(size_t)p * Q + q0 + tx];
        tile[ty + s][tx] = __float2bfloat16(v == 1 ? 1.0f : 0.0f);
    }
    __syncthreads();
    for (int s = 0; s < 32; s += 8) {
        Abt[(size_t)(q0 + ty + s) * Q + p0 + tx] = tile[tx][ty + s];
    }
}

// ---------------------------------------------------------------------------
// K3: GEMM  C[M,N] = A[M,K] * Bt[N,K]^T  (bf16 in, fp32 acc, bf16 out).
// 256x128 C-tile / 256-thread block, 2x2 waves, each wave 128x64 as an
// 8x4 grid of 16x16x32 MFMAs. Both operands LDS-staged via global_load_lds
// width-16 (R3 lesson: direct-global B fragments stall on L2 latency at
// 2 blocks/CU). 8x4 raises MFMA:ds_read ratio to 32/12=2.67 vs 4x4's 2.0 —
// the measured bottleneck is LDS read BW (R2: MfmaUtil 28% == 78cyc MFMA /
// 288cyc LDS phase). XOR chunk-swizzle (verified conflict-free in R3):
// physical 16B chunk cp at row r holds logical chunk cp ^ ((r>>1)&3).
__global__ __launch_bounds__(256, 2) void gemm_bt(const short* __restrict__ A,
                                                  const short* __restrict__ Bt,
                                                  __hip_bfloat16* __restrict__ C) {
    __shared__ short lds[12288];         // As: 256x32, Bs: 128x32
    short* As = lds;
    short* Bs = lds + 8192;

    const int t = threadIdx.x;
    const int w = t >> 6;                // wave 0..3
    const int wr = w >> 1, wc = w & 1;   // 2x2 wave grid
    const int l = t & 63;
    const int quad = l >> 4;             // 0..3
    const int lane16 = l & 15;

    const int m0 = blockIdx.x * 256;
    const int n0 = blockIdx.y * 128;

    // staging: thread t covers row (t>>2) within a 64-row call, 16B chunk
    // (t&3); global source column XOR-swizzled to match the LDS physical
    // layout (LDS dest is wave-uniform base + lane*16, lane-sequential).
    const int s_row = t >> 2;                          // 0..63
    const int s_col = ((t & 3) ^ ((t >> 3) & 3)) * 8;  // swizzled k-offset

    // fragment read: logical chunk `quad` at row (..+i*16+lane16) lives at
    // physical chunk quad ^ ((lane16>>1)&3)  (i*16 contributes 0 mod 8).
    const int a_chunk = (quad ^ ((lane16 >> 1) & 3)) * 8;

    f32x4 acc[8][4] = {};

    for (int k0 = 0; k0 < K_TOT; k0 += 32) {
        // A: 256 rows in 4 calls of 64 rows
        #pragma unroll
        for (int c = 0; c < 4; c++) {
            const short* gA = A + (size_t)(m0 + c * 64 + s_row) * K_TOT + k0 + s_col;
            __builtin_amdgcn_global_load_lds(
                (const __attribute__((address_space(1))) void*)gA,
                (__attribute__((address_space(3))) void*)(As + c * 2048 + w * 512),
                16, 0, 0);
        }
        // B: 128 rows in 2 calls
        #pragma unroll
        for (int c = 0; c < 2; c++) {
            const short* gB = Bt + (size_t)(n0 + c * 64 + s_row) * K_TOT + k0 + s_col;
            __builtin_amdgcn_global_load_lds(
                (const __attribute__((address_space(1))) void*)gB,
                (__attribute__((address_space(3))) void*)(Bs + c * 2048 + w * 512),
                16, 0, 0);
        }
        __syncthreads();

        short8 af[8], bfr[4];
        #pragma unroll
        for (int j = 0; j < 4; j++)
            bfr[j] = *(const short8*)(Bs + (wc * 64 + j * 16 + lane16) * 32 + a_chunk);
        #pragma unroll
        for (int i = 0; i < 8; i++)
            af[i] = *(const short8*)(As + (wr * 128 + i * 16 + lane16) * 32 + a_chunk);

        #pragma unroll
        for (int i = 0; i < 8; i++)
            #pragma unroll
            for (int j = 0; j < 4; j++)
                acc[i][j] = __builtin_amdgcn_mfma_f32_16x16x32_bf16(
                    af[i], bfr[j], acc[i][j], 0, 0, 0);
        __syncthreads();
    }

    // epilogue: C/D layout col = lane&15, row = quad*4 + reg
    #pragma unroll
    for (int i = 0; i < 8; i++) {
        #pragma unroll
        for (int j = 0; j < 4; j++) {
            #pragma unroll
            for (int r = 0; r < 4; r++) {
                int row = m0 + wr * 128 + i * 16 + quad * 4 + r;
                int col = n0 + wc * 64 + j * 16 + lane16;
                C[(size_t)row * N_TOT + col] = __float2bfloat16(acc[i][j][r]);
            }
        }
    }
}

// ---------------------------------------------------------------------------
// K4: per-edge dot. One wave per 4 edges; block = 4 waves = 16 edges of one
// batch. Lane l reads 4x16B chunks per row (whole Q=2048 row per wave,
// coalesced). One shuffle-reduce covers all 4 weighted dots (linearity).
// Also accumulates sum_e w (wave-uniform, free) for the finalize divide.
#define EPB 16   // edges per block
__global__ __launch_bounds__(256) void edge_dot(const __hip_bfloat16* __restrict__ PAb,
                                                const __hip_bfloat16* __restrict__ Pb,
                                                const int* __restrict__ esrc,
                                                const int* __restrict__ edst,
                                                const float* __restrict__ ew,
                                                float* __restrict__ adj_acc,
                                                float* __restrict__ wsum_acc) {
    const int b = blockIdx.y;
    const int t = threadIdx.x;
    const int w = t >> 6;
    const int l = t & 63;
    const int e_base = blockIdx.x * EPB + w * 4;

    const unsigned short* PAbase = (const unsigned short*)PAb + (size_t)b * NLOG * Q;
    const unsigned short* Pbase  = (const unsigned short*)Pb  + (size_t)b * NLOG * Q;

    float accw = 0.f, wsumw = 0.f;
    #pragma unroll
    for (int k = 0; k < 4; k++) {
        int e = e_base + k;
        int src = esrc[b * NEDGE + e];
        int dst = edst[b * NEDGE + e];
        float wgt = ew[b * NEDGE + e];
        wsumw += wgt;
        const unsigned short* gi = PAbase + (size_t)src * Q + l * 8;
        const unsigned short* gj = Pbase  + (size_t)dst * Q + l * 8;
        float s = 0.f;
        #pragma unroll
        for (int c = 0; c < 4; c++) {
            us8 a = *(const us8*)(gi + c * 512);
            us8 bb = *(const us8*)(gj + c * 512);
            #pragma unroll
            for (int u = 0; u < 8; u++) {
                float fa = __uint_as_float((unsigned)a[u] << 16);
                float fb = __uint_as_float((unsigned)bb[u] << 16);
                s += fa * fb;
            }
        }
        accw += wgt * s;
    }
    #pragma unroll
    for (int off = 32; off > 0; off >>= 1) accw += __shfl_xor(accw, off);
    __shared__ float wred[4], wred2[4];
    if (l == 0) { wred[w] = accw; wred2[w] = wsumw; }
    __syncthreads();
    if (t == 0) {
        atomicAdd(&adj_acc[b], wred[0] + wred[1] + wred[2] + wred[3]);
        atomicAdd(&wsum_acc[b], wred2[0] + wred2[1] + wred2[2] + wred2[3]);
    }
}

// ---------------------------------------------------------------------------
// K5: loss = -mean_b( adj[b] / max(wsum[b], eps) )
__global__ __launch_bounds__(64) void finalize(const float* __restrict__ adj_acc,
                                               const float* __restrict__ wsum_acc,
                                               float* __restrict__ out) {
    if (threadIdx.x == 0) {
        float s = 0.f;
        #pragma unroll
        for (int b = 0; b < BATCH; b++)
            s += adj_acc[b] / fmaxf(wsum_acc[b], 1e-8f);
        out[0] = -s / (float)BATCH;
    }
}

// ---------------------------------------------------------------------------
extern "C" void kernel_launch(void* const* d_in, const int* in_sizes, int n_in,
                              void* d_out, int out_size, void* d_ws, size_t ws_size,
                              hipStream_t stream) {
    const float* P    = (const float*)d_in[0];
    const int* d_hw   = (const int*)d_in[1];
    const int* esrc   = (const int*)d_in[2];
    const int* edst   = (const int*)d_in[3];
    const float* ew   = (const float*)d_in[4];
    float* out        = (float*)d_out;

    char* ws = (char*)d_ws;
    // workspace layout (bytes):
    //   Pb   : bf16 [B*N*Q]  = 33,554,432
    //   Abt  : bf16 [Q*Q]    =  8,388,608  (offset 33,554,432)
    //   PAb  : bf16 [B*N*Q]  = 33,554,432  (offset 41,943,040)
    //   adj  : f32 [16]                     (offset 75,497,472)
    //   wsum : f32 [16]                     (offset 75,497,536)
    __hip_bfloat16* Pb  = (__hip_bfloat16*)ws;
    __hip_bfloat16* Abt = (__hip_bfloat16*)(ws + 33554432);
    __hip_bfloat16* PAb = (__hip_bfloat16*)(ws + 41943040);
    float* adj          = (float*)(ws + 75497472);
    float* wsum         = (float*)(ws + 75497536);

    hipMemsetAsync(adj, 0, 2 * BATCH * sizeof(float), stream);

    cvt_p<<<M_TOT * Q / (256 * 8), 256, 0, stream>>>(P, Pb);
    build_abt<<<dim3(Q / 32, Q / 32), 256, 0, stream>>>(d_hw, Abt);
    gemm_bt<<<dim3(M_TOT / 256, N_TOT / 128), 256, 0, stream>>>(
        (const short*)Pb, (const short*)Abt, PAb);
    edge_dot<<<dim3(NEDGE / EPB, BATCH), 256, 0, stream>>>(
        PAb, Pb, esrc, edst, ew, adj, wsum);
    finalize<<<1, 64, 0, stream>>>(adj, wsum, out);
}

// Round 5
// 230.549 us; speedup vs baseline: 1.3527x; 1.0206x over previous
//
#include <hip/hip_runtime.h>
#include <hip/hip_bf16.h>

// Problem sizes (fixed by reference setup_inputs):
//   B=16, N_LOG=512, N_PHYS(Q)=2048, E=2048
#define BATCH 16
#define NLOG 512
#define Q 2048
#define NEDGE 2048
#define M_TOT (BATCH * NLOG)   // 8192 GEMM rows
#define K_TOT Q                // 2048
#define N_TOT Q                // 2048

typedef short short8 __attribute__((ext_vector_type(8)));
typedef float f32x4 __attribute__((ext_vector_type(4)));
typedef unsigned short us8 __attribute__((ext_vector_type(8)));

// ---------------------------------------------------------------------------
// K1: convert P (fp32) -> Pb (bf16). 16.78M elements, 8 per thread,
// packed 16B store.
__global__ __launch_bounds__(256) void cvt_p(const float* __restrict__ P,
                                             __hip_bfloat16* __restrict__ Pb) {
    int i = (blockIdx.x * 256 + threadIdx.x) * 8;
    float4 v0 = *(const float4*)(P + i);
    float4 v1 = *(const float4*)(P + i + 4);
    __hip_bfloat16 tmp[8];
    tmp[0] = __float2bfloat16(v0.x);
    tmp[1] = __float2bfloat16(v0.y);
    tmp[2] = __float2bfloat16(v0.z);
    tmp[3] = __float2bfloat16(v0.w);
    tmp[4] = __float2bfloat16(v1.x);
    tmp[5] = __float2bfloat16(v1.y);
    tmp[6] = __float2bfloat16(v1.z);
    tmp[7] = __float2bfloat16(v1.w);
    *(short8*)(Pb + i) = *(short8*)tmp;
}

// ---------------------------------------------------------------------------
// K2: build Abt[q][p] = (d_hw[p][q] == 1) ? 1 : 0 (bf16), via 32x32 LDS
// transpose so both global read and write are coalesced.
__global__ __launch_bounds__(256) void build_abt(const int* __restrict__ d_hw,
                                                 __hip_bfloat16* __restrict__ Abt) {
    __shared__ __hip_bfloat16 tile[32][33];
    int q0 = blockIdx.x * 32;
    int p0 = blockIdx.y * 32;
    int tx = threadIdx.x & 31;
    int ty = threadIdx.x >> 5;  // 0..7
    for (int s = 0; s < 32; s += 8) {
        int p = p0 + ty + s;
        int v = d_hw[(size_t)p * Q + q0 + tx];
        tile[ty + s][tx] = __float2bfloat16(v == 1 ? 1.0f : 0.0f);
    }
    __syncthreads();
    for (int s = 0; s < 32; s += 8) {
        Abt[(size_t)(q0 + ty + s) * Q + p0 + tx] = tile[tx][ty + s];
    }
}

// ---------------------------------------------------------------------------
// K3: main GEMM  PA[M,N] = P[M,K] * Abt[N,K]^T  (bf16 in, fp32 acc, bf16
// out). 256x128 C-tile / 256-thread block, 2x2 waves, each wave 128x64 as
// an 8x4 grid of 16x16x32 MFMAs (MFMA:ds_read = 32/12). Both operands LDS-
// staged via global_load_lds width-16; XOR chunk-swizzle (verified
// conflict-free R3/R4): physical 16B chunk cp at row r holds logical chunk
// cp ^ ((r>>1)&3).
__global__ __launch_bounds__(256, 2) void gemm_bt(const short* __restrict__ A,
                                                  const short* __restrict__ Bt,
                                                  __hip_bfloat16* __restrict__ C) {
    __shared__ short lds[12288];         // As: 256x32, Bs: 128x32
    short* As = lds;
    short* Bs = lds + 8192;

    const int t = threadIdx.x;
    const int w = t >> 6;                // wave 0..3
    const int wr = w >> 1, wc = w & 1;   // 2x2 wave grid
    const int l = t & 63;
    const int quad = l >> 4;             // 0..3
    const int lane16 = l & 15;

    const int m0 = blockIdx.x * 256;
    const int n0 = blockIdx.y * 128;

    const int s_row = t >> 2;                          // 0..63
    const int s_col = ((t & 3) ^ ((t >> 3) & 3)) * 8;  // swizzled k-offset
    const int a_chunk = (quad ^ ((lane16 >> 1) & 3)) * 8;

    f32x4 acc[8][4] = {};

    for (int k0 = 0; k0 < K_TOT; k0 += 32) {
        #pragma unroll
        for (int c = 0; c < 4; c++) {
            const short* gA = A + (size_t)(m0 + c * 64 + s_row) * K_TOT + k0 + s_col;
            __builtin_amdgcn_global_load_lds(
                (const __attribute__((address_space(1))) void*)gA,
                (__attribute__((address_space(3))) void*)(As + c * 2048 + w * 512),
                16, 0, 0);
        }
        #pragma unroll
        for (int c = 0; c < 2; c++) {
            const short* gB = Bt + (size_t)(n0 + c * 64 + s_row) * K_TOT + k0 + s_col;
            __builtin_amdgcn_global_load_lds(
                (const __attribute__((address_space(1))) void*)gB,
                (__attribute__((address_space(3))) void*)(Bs + c * 2048 + w * 512),
                16, 0, 0);
        }
        __syncthreads();

        short8 af[8], bfr[4];
        #pragma unroll
        for (int j = 0; j < 4; j++)
            bfr[j] = *(const short8*)(Bs + (wc * 64 + j * 16 + lane16) * 32 + a_chunk);
        #pragma unroll
        for (int i = 0; i < 8; i++)
            af[i] = *(const short8*)(As + (wr * 128 + i * 16 + lane16) * 32 + a_chunk);

        #pragma unroll
        for (int i = 0; i < 8; i++)
            #pragma unroll
            for (int j = 0; j < 4; j++)
                acc[i][j] = __builtin_amdgcn_mfma_f32_16x16x32_bf16(
                    af[i], bfr[j], acc[i][j], 0, 0, 0);
        __syncthreads();
    }

    #pragma unroll
    for (int i = 0; i < 8; i++) {
        #pragma unroll
        for (int j = 0; j < 4; j++) {
            #pragma unroll
            for (int r = 0; r < 4; r++) {
                int row = m0 + wr * 128 + i * 16 + quad * 4 + r;
                int col = n0 + wc * 64 + j * 16 + lane16;
                C[(size_t)row * N_TOT + col] = __float2bfloat16(acc[i][j][r]);
            }
        }
    }
}

// ---------------------------------------------------------------------------
// K4: score GEMM  S_b[i,j] = sum_q PA_b[i,q] * P_b[j,q]  per batch.
// M=N=512, K=2048 -> 17.2 GFLOP total (25% of main GEMM). Replaces the
// 256 MB edge row-gather with a streamed GEMM; edges then need only scalar
// S lookups. 128x128 tile, 2x2 waves, 4x4 MFMAs each, same verified
// swizzle/staging as gemm_bt. Grid (4,4,16).
__global__ __launch_bounds__(256, 2) void gemm_s(const short* __restrict__ PAb,
                                                 const short* __restrict__ Pb,
                                                 __hip_bfloat16* __restrict__ S) {
    __shared__ short lds[8192];          // As: 128x32, Bs: 128x32
    short* As = lds;
    short* Bs = lds + 4096;

    const int t = threadIdx.x;
    const int w = t >> 6;
    const int wr = w >> 1, wc = w & 1;
    const int l = t & 63;
    const int quad = l >> 4;
    const int lane16 = l & 15;

    const int b = blockIdx.z;
    const int m0 = blockIdx.x * 128;
    const int n0 = blockIdx.y * 128;
    const short* A  = PAb + (size_t)b * NLOG * Q;
    const short* Bt = Pb  + (size_t)b * NLOG * Q;
    __hip_bfloat16* C = S + (size_t)b * NLOG * NLOG;

    const int s_row = t >> 2;
    const int s_col = ((t & 3) ^ ((t >> 3) & 3)) * 8;
    const int a_chunk = (quad ^ ((lane16 >> 1) & 3)) * 8;

    f32x4 acc[4][4] = {};

    for (int k0 = 0; k0 < Q; k0 += 32) {
        #pragma unroll
        for (int c = 0; c < 2; c++) {
            const short* gA = A + (size_t)(m0 + c * 64 + s_row) * Q + k0 + s_col;
            __builtin_amdgcn_global_load_lds(
                (const __attribute__((address_space(1))) void*)gA,
                (__attribute__((address_space(3))) void*)(As + c * 2048 + w * 512),
                16, 0, 0);
            const short* gB = Bt + (size_t)(n0 + c * 64 + s_row) * Q + k0 + s_col;
            __builtin_amdgcn_global_load_lds(
                (const __attribute__((address_space(1))) void*)gB,
                (__attribute__((address_space(3))) void*)(Bs + c * 2048 + w * 512),
                16, 0, 0);
        }
        __syncthreads();

        short8 af[4], bfr[4];
        #pragma unroll
        for (int i = 0; i < 4; i++) {
            af[i]  = *(const short8*)(As + (wr * 64 + i * 16 + lane16) * 32 + a_chunk);
            bfr[i] = *(const short8*)(Bs + (wc * 64 + i * 16 + lane16) * 32 + a_chunk);
        }
        #pragma unroll
        for (int i = 0; i < 4; i++)
            #pragma unroll
            for (int j = 0; j < 4; j++)
                acc[i][j] = __builtin_amdgcn_mfma_f32_16x16x32_bf16(
                    af[i], bfr[j], acc[i][j], 0, 0, 0);
        __syncthreads();
    }

    #pragma unroll
    for (int i = 0; i < 4; i++) {
        #pragma unroll
        for (int j = 0; j < 4; j++) {
            #pragma unroll
            for (int r = 0; r < 4; r++) {
                int row = m0 + wr * 64 + i * 16 + quad * 4 + r;
                int col = n0 + wc * 64 + j * 16 + lane16;
                C[(size_t)row * NLOG + col] = __float2bfloat16(acc[i][j][r]);
            }
        }
    }
}

// ---------------------------------------------------------------------------
// K5: per-batch edge reduction via scalar S-gather. One block per batch;
// S_b is 0.5 MB (L2-resident). No atomics: block b owns adj[b]/wsum[b].
__global__ __launch_bounds__(256) void edge_gather(const __hip_bfloat16* __restrict__ S,
                                                   const int* __restrict__ esrc,
                                                   const int* __restrict__ edst,
                                                   const float* __restrict__ ew,
                                                   float* __restrict__ adj,
                                                   float* __restrict__ wsum) {
    const int b = blockIdx.x;
    const int t = threadIdx.x;
    const unsigned short* Sb = (const unsigned short*)S + (size_t)b * NLOG * NLOG;
    float a = 0.f, ws = 0.f;
    #pragma unroll
    for (int k = 0; k < NEDGE / 256; k++) {
        int e = b * NEDGE + k * 256 + t;
        int src = esrc[e];
        int dst = edst[e];
        float wg = ew[e];
        float s = __uint_as_float((unsigned)Sb[src * NLOG + dst] << 16);
        a += wg * s;
        ws += wg;
    }
    #pragma unroll
    for (int off = 32; off > 0; off >>= 1) {
        a += __shfl_xor(a, off);
        ws += __shfl_xor(ws, off);
    }
    __shared__ float ra[4], rw[4];
    if ((t & 63) == 0) { ra[t >> 6] = a; rw[t >> 6] = ws; }
    __syncthreads();
    if (t == 0) {
        adj[b]  = ra[0] + ra[1] + ra[2] + ra[3];
        wsum[b] = rw[0] + rw[1] + rw[2] + rw[3];
    }
}

// ---------------------------------------------------------------------------
// K6: loss = -mean_b( adj[b] / max(wsum[b], eps) )
__global__ __launch_bounds__(64) void finalize(const float* __restrict__ adj,
                                               const float* __restrict__ wsum,
                                               float* __restrict__ out) {
    if (threadIdx.x == 0) {
        float s = 0.f;
        #pragma unroll
        for (int b = 0; b < BATCH; b++)
            s += adj[b] / fmaxf(wsum[b], 1e-8f);
        out[0] = -s / (float)BATCH;
    }
}

// ---------------------------------------------------------------------------
extern "C" void kernel_launch(void* const* d_in, const int* in_sizes, int n_in,
                              void* d_out, int out_size, void* d_ws, size_t ws_size,
                              hipStream_t stream) {
    const float* P    = (const float*)d_in[0];
    const int* d_hw   = (const int*)d_in[1];
    const int* esrc   = (const int*)d_in[2];
    const int* edst   = (const int*)d_in[3];
    const float* ew   = (const float*)d_in[4];
    float* out        = (float*)d_out;

    char* ws = (char*)d_ws;
    // workspace layout (bytes):
    //   Pb   : bf16 [B*N*Q]   = 33,554,432   [0, 33.5M)
    //   Abt  : bf16 [Q*Q]     =  8,388,608   [33.5M, 41.9M)  -- dead after gemm_bt
    //   S    : bf16 [B*N*N]   =  8,388,608   ALIASES Abt slot (exact fit)
    //   PAb  : bf16 [B*N*Q]   = 33,554,432   [41.9M, 75.5M)
    //   adj  : f32 [16]                       (75,497,472)
    //   wsum : f32 [16]                       (75,497,536)
    __hip_bfloat16* Pb  = (__hip_bfloat16*)ws;
    __hip_bfloat16* Abt = (__hip_bfloat16*)(ws + 33554432);
    __hip_bfloat16* S   = (__hip_bfloat16*)(ws + 33554432);  // reuse Abt slot
    __hip_bfloat16* PAb = (__hip_bfloat16*)(ws + 41943040);
    float* adj          = (float*)(ws + 75497472);
    float* wsum         = (float*)(ws + 75497536);

    cvt_p<<<M_TOT * Q / (256 * 8), 256, 0, stream>>>(P, Pb);
    build_abt<<<dim3(Q / 32, Q / 32), 256, 0, stream>>>(d_hw, Abt);
    gemm_bt<<<dim3(M_TOT / 256, N_TOT / 128), 256, 0, stream>>>(
        (const short*)Pb, (const short*)Abt, PAb);
    gemm_s<<<dim3(NLOG / 128, NLOG / 128, BATCH), 256, 0, stream>>>(
        (const short*)PAb, (const short*)Pb, S);
    edge_gather<<<BATCH, 256, 0, stream>>>(S, esrc, edst, ew, adj, wsum);
    finalize<<<1, 64, 0, stream>>>(adj, wsum, out);
}